// Round 15
// baseline (53.538 us; speedup 1.0000x reference)
//
#include <hip/hip_runtime.h>
#include <cstdint>

#define TOK 2048
#define EMB 768
#define WIN 64
#define TCN (TOK / 16) // 128 token tiles (16-row)
#define DCN (EMB / 32) // 24 d-chunks (32-col)

typedef __attribute__((ext_vector_type(8))) __bf16 bf16x8;
typedef __attribute__((ext_vector_type(4))) float f32x4;

static __device__ __forceinline__ unsigned short f2bf(float f) {
  uint32_t x = __float_as_uint(f);
  uint32_t r = (x + 0x7fffu + ((x >> 16) & 1u)) >> 16;  // RNE
  return (unsigned short)r;
}

static __device__ __forceinline__ void gload_lds16(const void* g, void* l) {
  __builtin_amdgcn_global_load_lds(
      (const __attribute__((address_space(1))) uint32_t*)g,
      (__attribute__((address_space(3))) uint32_t*)l, 16, 0, 0);
}

// ---------------- prep: weights -> transposed bf16 WT[d][e] ----------------
__global__ __launch_bounds__(256) void prep_w(
    const float* __restrict__ Wk, const float* __restrict__ Wv,
    const float* __restrict__ Wq, unsigned short* __restrict__ WT) {
  __shared__ float t[32][33];
  const int bx = blockIdx.x, tid = threadIdx.x;
  const int wz = bx / 576, rem = bx - wz * 576;
  const float* w = (wz == 0) ? Wk : (wz == 1) ? Wv : Wq;
  const int d0 = (rem % 24) * 32, e0 = (rem / 24) * 32;
  const int tx = tid & 31, ty = tid >> 5;  // (32,8)
#pragma unroll
  for (int r = 0; r < 4; ++r)
    t[ty + r * 8][tx] = w[(size_t)(e0 + ty + r * 8) * EMB + d0 + tx];
  __syncthreads();
#pragma unroll
  for (int r = 0; r < 4; ++r) {
    const int dl = ty + r * 8, el = tx;
    WT[(size_t)wz * EMB * EMB + (size_t)(d0 + dl) * EMB + e0 + el] =
        f2bf(t[el][dl]);
  }
}

// ---------------- projections: bf16 MFMA GEMM, fp32-A direct, dbuf ---------
// C = A@W with A staged RAW fp32 via global_load_lds into a dbuf (fire-and-
// forget, drains at the same barrier as B -> staging off the critical path,
// unlike r9/serial). fp32->bf16 happens at the fragment read (2x ds_read_b128
// + v_cvt_pk, VALU overlaps MFMA). Deletes the input-conversion prep pass.
// A swizzle: 16-slot involution (slot ^ row&15), pre-swizzled SOURCE +
// same XOR at read (rule #21). B: bf16 gload_lds + 8-slot involution (r10).
// BK=64, BN=96 -> 768 blocks; LDS 56KB -> 2 blocks/CU.
// Epilogue writes MFMA-native layouts:
//   z=0 (k), z=2 (q): bf16 tiled [tok/16][d/32][16][32]
//   z=1 (v): bf16 V^T panels [tok/32][768][32]
__global__ __launch_bounds__(256) void proj_gemm(
    const float* __restrict__ key, const float* __restrict__ value,
    const float* __restrict__ query, const unsigned short* __restrict__ WT,
    unsigned short* __restrict__ k_t, unsigned short* __restrict__ vT_p,
    unsigned short* __restrict__ q_t) {
  const int z = blockIdx.z;
  const float* __restrict__ Af = (z == 0) ? key : (z == 1) ? value : query;
  const int bn0 = blockIdx.x * 96;   // output col (D)
  const int bm0 = blockIdx.y * 64;   // output row (token)
  const int tid = threadIdx.x, lane = tid & 63, w = tid >> 6;
  const int wr = w >> 1, wc = w & 1;
  const int l15 = lane & 15, l4 = lane >> 4;

  __shared__ float lAf[2][64 * 64];           // 2 x 16KB (fp32 A)
  __shared__ unsigned short lB[2][96 * 64];   // 2 x 12KB (bf16 B)

  const unsigned short* __restrict__ Bh = WT + (size_t)z * EMB * EMB;

  f32x4 acc[2][3] = {};

  // A staging: 16 x 1KB chunks (4 rows x 16 slots of 16B each); 4 per wave.
  const int sarow = lane >> 4;   // row within 4-row group
  const int sachk = lane & 15;   // 16B slot
  // B staging: 12 x 1KB chunks (8 rows x 8 slots); 3 per wave.
  const int srow = lane >> 3;
  const int scol = ((lane & 7) ^ (srow & 7)) * 8;

  auto STAGE = [&](int b, int kt) {
    const int kk = kt * 64;
#pragma unroll
    for (int c = 0; c < 4; ++c) {
      const int ch = w * 4 + c;            // 0..15
      const int row = ch * 4 + sarow;      // 0..63
      const int sc4 = (sachk ^ (row & 15)) * 4;  // fp32 col (16B chunks)
      gload_lds16(Af + (size_t)(bm0 + row) * EMB + kk + sc4,
                  (char*)&lAf[b][0] + ch * 1024);
    }
#pragma unroll
    for (int c = 0; c < 3; ++c) {
      const int ch = w * 3 + c;  // 12 B-chunks (96 rows)
      gload_lds16(Bh + (size_t)(bn0 + ch * 8 + srow) * EMB + kk + scol,
                  (char*)&lB[b][0] + ch * 1024);
    }
  };

  auto COMPUTE = [&](int b) {
#pragma unroll
    for (int ks = 0; ks < 2; ++ks) {
      bf16x8 af[2], bfr[3];
#pragma unroll
      for (int m = 0; m < 2; ++m) {
        const int R = wr * 32 + m * 16 + l15;
        const int c2 = (ks * 4 + l4) * 2;  // even global chunk index
        const float4 f0 = *(const float4*)((const char*)&lAf[b][0] + R * 256 +
                                           ((c2 ^ (R & 15)) * 16));
        const float4 f1 = *(const float4*)((const char*)&lAf[b][0] + R * 256 +
                                           (((c2 + 1) ^ (R & 15)) * 16));
        bf16x8 av;
        av[0] = (__bf16)f0.x; av[1] = (__bf16)f0.y;
        av[2] = (__bf16)f0.z; av[3] = (__bf16)f0.w;
        av[4] = (__bf16)f1.x; av[5] = (__bf16)f1.y;
        av[6] = (__bf16)f1.z; av[7] = (__bf16)f1.w;
        af[m] = av;
      }
#pragma unroll
      for (int n = 0; n < 3; ++n) {
        const int R = wc * 48 + n * 16 + l15;
        const int sl = (ks * 4 + l4) ^ (R & 7);
        bfr[n] = *(const bf16x8*)((const char*)&lB[b][0] + R * 128 + sl * 16);
      }
#pragma unroll
      for (int m = 0; m < 2; ++m)
#pragma unroll
        for (int n = 0; n < 3; ++n)
          acc[m][n] = __builtin_amdgcn_mfma_f32_16x16x32_bf16(af[m], bfr[n],
                                                              acc[m][n], 0, 0, 0);
    }
  };

  STAGE(0, 0);
  __syncthreads();  // prologue drain
#pragma unroll
  for (int kt = 0; kt < 12; kt += 2) {
    if (kt + 1 < 12) STAGE(1, kt + 1);
    COMPUTE(0);
    __syncthreads();
    if (kt + 2 < 12) STAGE(0, kt + 2);
    COMPUTE(1);
    __syncthreads();
  }

  // ---- epilogue: write MFMA-native layouts ----
  if (z == 1) {
#pragma unroll
    for (int m = 0; m < 2; ++m) {
      const int tok0 = bm0 + wr * 32 + m * 16 + l4 * 4;
#pragma unroll
      for (int n = 0; n < 3; ++n) {
        const int d = bn0 + wc * 48 + n * 16 + l15;
        ushort4 pk;
        pk.x = f2bf(acc[m][n][0]); pk.y = f2bf(acc[m][n][1]);
        pk.z = f2bf(acc[m][n][2]); pk.w = f2bf(acc[m][n][3]);
        *(ushort4*)&vT_p[(((size_t)(tok0 >> 5) * EMB + d) << 5) + (tok0 & 31)] = pk;
      }
    }
  } else {
    unsigned short* __restrict__ dh = (z == 0) ? k_t : q_t;
#pragma unroll
    for (int m = 0; m < 2; ++m) {
      const int tok0 = bm0 + wr * 32 + m * 16 + l4 * 4;
#pragma unroll
      for (int n = 0; n < 3; ++n) {
        const int d = bn0 + wc * 48 + n * 16 + l15;
        const size_t base =
            (((size_t)(tok0 >> 4) * DCN + (d >> 5)) * 16) * 32 + (d & 31);
#pragma unroll
        for (int r = 0; r < 4; ++r)
          dh[base + (size_t)((tok0 & 15) + r) * 32] = f2bf(acc[m][n][r]);
      }
    }
  }
}

// ---------------- fused attention: QK^T -> exp -> P(LDS) -> PV -------------
// 256 blocks = (qt 0..127) x (h 0..1); 384 threads = 6 waves.
// Phase 1: wave w owns N-tiles {2w, 2w+1} (2 indep MFMA chains); P -> LDS
// chunk P_l[w] (bf16 A-layout) + partial row sums. QK^T duplicated across
// the 2 h-blocks (cheap) to keep 256 blocks resident.
// Phase 2: wave w owns 64 d-cols of half h; PV from P_l + vT_p panels;
// normalize by 1/(rowsum*L) (tid<16 via LDS). No Pg/Ssum global traffic.
__global__ __launch_bounds__(384) void attn_fused(
    const unsigned short* __restrict__ k_t, const unsigned short* __restrict__ q_t,
    const unsigned short* __restrict__ vT_p, float* __restrict__ out) {
  const int bid = ((int)blockIdx.x & 7) * 32 + ((int)blockIdx.x >> 3);  // XCD
  const int qt = bid >> 1, h = bid & 1;
  const int tid = threadIdx.x, lane = tid & 63, w = tid / 64;  // 0..5
  const int l15 = lane & 15, l4 = lane >> 4;
  const int t0 = qt * 16;
  const int js0 = (t0 - 64) & ~31;  // 32-aligned slot base (maybe <0)

  __shared__ unsigned short P_l[6][16][32];  // 6KB
  __shared__ float ssum_l[12][16];
  __shared__ float rcp_l[16];

  const int foff = l15 * 32 + l4 * 8;
  const size_t a_base = (size_t)qt * DCN * 512 + foff;

  // ---- phase 1: QK^T for N-tiles 2w, 2w+1 ----
  const int tt0 = min(max((js0 >> 4) + 2 * w, 0), TCN - 1);
  const int tt1 = min(max((js0 >> 4) + 2 * w + 1, 0), TCN - 1);
  const size_t b0 = (size_t)tt0 * DCN * 512 + foff;
  const size_t b1 = (size_t)tt1 * DCN * 512 + foff;

  f32x4 s0 = {}, s1 = {};
#pragma unroll
  for (int kk = 0; kk < DCN; ++kk) {
    const bf16x8 ah = *(const bf16x8*)&q_t[a_base + (size_t)kk * 512];
    const bf16x8 bb0 = *(const bf16x8*)&k_t[b0 + (size_t)kk * 512];
    const bf16x8 bb1 = *(const bf16x8*)&k_t[b1 + (size_t)kk * 512];
    s0 = __builtin_amdgcn_mfma_f32_16x16x32_bf16(ah, bb0, s0, 0, 0, 0);
    s1 = __builtin_amdgcn_mfma_f32_16x16x32_bf16(ah, bb1, s1, 0, 0, 0);
  }

  const float SC = 0.03608439182435161f;  // 768^-0.5
  const int qrow0 = t0 + l4 * 4;
#pragma unroll
  for (int half = 0; half < 2; ++half) {
    const int nt = 2 * w + half;
    const f32x4 sv = half ? s1 : s0;
    const int j = js0 + nt * 16 + l15;
    float e[4];
#pragma unroll
    for (int r = 0; r < 4; ++r) {
      const int t = qrow0 + r;
      const bool ok = (j >= 0) && (j < TOK) && (j >= t - WIN) && (j <= t + WIN);
      e[r] = ok ? __expf(sv[r] * SC) : 0.0f;
    }
#pragma unroll
    for (int r = 0; r < 4; ++r) {
      float sm = e[r];
#pragma unroll
      for (int off = 1; off < 16; off <<= 1) sm += __shfl_xor(sm, off);
      if (l15 == 0) ssum_l[nt][l4 * 4 + r] = sm;
    }
#pragma unroll
    for (int r = 0; r < 4; ++r)
      P_l[w][l4 * 4 + r][half * 16 + l15] = f2bf(e[r]);
  }
  __syncthreads();

  if (tid < 16) {
    float s = 0.f;
#pragma unroll
    for (int i = 0; i < 12; ++i) s += ssum_l[i][tid];
    const int t = t0 + tid;
    const int len = min(TOK, t + WIN + 1) - max(0, t - WIN);
    rcp_l[tid] = 1.0f / (s * (float)len);
  }

  // ---- phase 2: PV, wave owns d-cols h*384 + w*64 .. +64 ----
  f32x4 o[4] = {};
  const int c0 = js0 >> 5;
#pragma unroll
  for (int kc = 0; kc < 6; ++kc) {
    const bf16x8 pa = *(const bf16x8*)&P_l[kc][l15][l4 * 8];
    const int cc = min(max(c0 + kc, 0), TOK / 32 - 1);  // clamp; P=0 masks
    const size_t vb = (size_t)cc * (EMB * 32);
#pragma unroll
    for (int n = 0; n < 4; ++n) {
      const int d = h * 384 + w * 64 + n * 16 + l15;
      const bf16x8 vbf = *(const bf16x8*)&vT_p[vb + (size_t)d * 32 + l4 * 8];
      o[n] = __builtin_amdgcn_mfma_f32_16x16x32_bf16(pa, vbf, o[n], 0, 0, 0);
    }
  }
  __syncthreads();  // rcp_l ready

  float rr[4];
#pragma unroll
  for (int r = 0; r < 4; ++r) rr[r] = rcp_l[l4 * 4 + r];
#pragma unroll
  for (int n = 0; n < 4; ++n) {
    const int d = h * 384 + w * 64 + n * 16 + l15;
#pragma unroll
    for (int r = 0; r < 4; ++r)
      out[(size_t)(qrow0 + r) * EMB + d] = o[n][r] * rr[r];
  }
}

extern "C" void kernel_launch(void* const* d_in, const int* in_sizes, int n_in,
                              void* d_out, int out_size, void* d_ws, size_t ws_size,
                              hipStream_t stream) {
  const float* key = (const float*)d_in[0];
  const float* value = (const float*)d_in[1];
  const float* query = (const float*)d_in[2];
  const float* Wk = (const float*)d_in[3];
  const float* Wv = (const float*)d_in[4];
  const float* Wq = (const float*)d_in[5];

  // ws layout (~13 MB): WT | k_t | q_t | vT_p
  unsigned short* ws = (unsigned short*)d_ws;
  const size_t NW = (size_t)3 * EMB * EMB;
  const size_t NM = (size_t)TOK * EMB;
  unsigned short* WT = ws;
  unsigned short* k_t = WT + NW;
  unsigned short* q_t = k_t + NM;
  unsigned short* vT_p = q_t + NM;
  float* out = (float*)d_out;

  prep_w<<<1728, 256, 0, stream>>>(Wk, Wv, Wq, WT);
  proj_gemm<<<dim3(EMB / 96, TOK / 64, 3), 256, 0, stream>>>(
      key, value, query, WT, k_t, vT_p, q_t);
  attn_fused<<<256, 384, 0, stream>>>(k_t, q_t, vT_p, out);
}

// Round 16
// 44.726 us; speedup vs baseline: 1.1970x; 1.1970x over previous
//
#include <hip/hip_runtime.h>
#include <cstdint>

#define TOK 2048
#define EMB 768
#define WIN 64
#define TCN (TOK / 16) // 128 token tiles (16-row)
#define DCN (EMB / 32) // 24 d-chunks (32-col)

typedef __attribute__((ext_vector_type(8))) __bf16 bf16x8;
typedef __attribute__((ext_vector_type(4))) float f32x4;

static __device__ __forceinline__ unsigned short f2bf(float f) {
  uint32_t x = __float_as_uint(f);
  uint32_t r = (x + 0x7fffu + ((x >> 16) & 1u)) >> 16;  // RNE
  return (unsigned short)r;
}

static __device__ __forceinline__ void gload_lds16(const void* g, void* l) {
  __builtin_amdgcn_global_load_lds(
      (const __attribute__((address_space(1))) uint32_t*)g,
      (__attribute__((address_space(3))) uint32_t*)l, 16, 0, 0);
}

// ---------------- prep (merged): z=0 inputs->bf16, z=1 weights->WT ---------
// z=1 vectorized: float4 loads, ushort4 stores (G13), LDS stride-33.
__global__ __launch_bounds__(256) void prep(
    const float* __restrict__ key, const float* __restrict__ value,
    const float* __restrict__ query, const float* __restrict__ Wk,
    const float* __restrict__ Wv, const float* __restrict__ Wq,
    unsigned short* __restrict__ Ab, unsigned short* __restrict__ WT) {
  __shared__ float t[32][33];
  const int z = blockIdx.z, bx = blockIdx.x, tid = threadIdx.x;
  if (z == 0) {
    const int64_t NE4 = (int64_t)TOK * EMB / 4;  // float4 per input
    const int64_t i = (int64_t)bx * 256 + tid;   // grid z=0 sized 3*NE4/256
    const int which = (int)(i / NE4);
    const int64_t loc = i - (int64_t)which * NE4;
    const float4* src =
        (const float4*)(which == 0 ? key : which == 1 ? value : query);
    const float4 x = src[loc];
    ushort4 h;
    h.x = f2bf(x.x); h.y = f2bf(x.y); h.z = f2bf(x.z); h.w = f2bf(x.w);
    ((ushort4*)Ab)[i] = h;
  } else {
    if (bx >= 1728) return;
    const int wz = bx / 576, rem = bx - wz * 576;
    const float* w = (wz == 0) ? Wk : (wz == 1) ? Wv : Wq;
    const int d0 = (rem % 24) * 32, e0 = (rem / 24) * 32;
    const int row = tid >> 3, c4 = (tid & 7) * 4;
    const float4 x = *(const float4*)&w[(size_t)(e0 + row) * EMB + d0 + c4];
    t[row][c4] = x.x; t[row][c4 + 1] = x.y;
    t[row][c4 + 2] = x.z; t[row][c4 + 3] = x.w;
    __syncthreads();
    // t[e][d] = W[e0+e][d0+d]; write WT[d][e] with ushort4 along e
    ushort4 pk;
    pk.x = f2bf(t[c4][row]); pk.y = f2bf(t[c4 + 1][row]);
    pk.z = f2bf(t[c4 + 2][row]); pk.w = f2bf(t[c4 + 3][row]);
    *(ushort4*)&WT[(size_t)wz * EMB * EMB + (size_t)(d0 + row) * EMB + e0 + c4] = pk;
  }
}

// ---------------- projections: bf16 MFMA GEMM, BK=64, dbuf, BN=96 ----------
// r12's proven kernel. STAGE(next) before COMPUTE(cur), one barrier per
// K-step; 768 blocks = 3.00/CU; T2 XOR involution on staging source + read.
// Epilogue writes MFMA-native layouts:
//   z=0 (k), z=2 (q): bf16 tiled [tok/16][d/32][16][32]
//   z=1 (v): bf16 V^T panels [tok/32][768][32]
__global__ __launch_bounds__(256) void proj_gemm(
    const unsigned short* __restrict__ Ab, const unsigned short* __restrict__ WT,
    unsigned short* __restrict__ k_t, unsigned short* __restrict__ vT_p,
    unsigned short* __restrict__ q_t) {
  const int z = blockIdx.z;
  const int bn0 = blockIdx.x * 96;   // output col (D)
  const int bm0 = blockIdx.y * 64;   // output row (token)
  const int tid = threadIdx.x, lane = tid & 63, w = tid >> 6;
  const int wr = w >> 1, wc = w & 1;
  const int l15 = lane & 15, l4 = lane >> 4;

  __shared__ unsigned short lA[2][64 * 64];   // 2 x 8KB
  __shared__ unsigned short lB[2][96 * 64];   // 2 x 12KB

  const unsigned short* __restrict__ Ah = Ab + (size_t)z * TOK * EMB;
  const unsigned short* __restrict__ Bh = WT + (size_t)z * EMB * EMB;

  f32x4 acc[2][3] = {};

  const int srow = lane >> 3;                       // row within chunk group
  const int scol = ((lane & 7) ^ (srow & 7)) * 8;   // bf16 col (16B chunks)

  auto STAGE = [&](int b, int kt) {
    const int kk = kt * 64;
#pragma unroll
    for (int c = 0; c < 2; ++c) {
      const int ch = w * 2 + c;  // 8 A-chunks (64 rows)
      gload_lds16(Ah + (size_t)(bm0 + ch * 8 + srow) * EMB + kk + scol,
                  (char*)&lA[b][0] + ch * 1024);
    }
#pragma unroll
    for (int c = 0; c < 3; ++c) {
      const int ch = w * 3 + c;  // 12 B-chunks (96 rows)
      gload_lds16(Bh + (size_t)(bn0 + ch * 8 + srow) * EMB + kk + scol,
                  (char*)&lB[b][0] + ch * 1024);
    }
  };

  auto COMPUTE = [&](int b) {
#pragma unroll
    for (int ks = 0; ks < 2; ++ks) {
      bf16x8 af[2], bfr[3];
#pragma unroll
      for (int m = 0; m < 2; ++m) {
        const int R = wr * 32 + m * 16 + l15;
        const int sl = (ks * 4 + l4) ^ (R & 7);
        af[m] = *(const bf16x8*)((const char*)&lA[b][0] + R * 128 + sl * 16);
      }
#pragma unroll
      for (int n = 0; n < 3; ++n) {
        const int R = wc * 48 + n * 16 + l15;
        const int sl = (ks * 4 + l4) ^ (R & 7);
        bfr[n] = *(const bf16x8*)((const char*)&lB[b][0] + R * 128 + sl * 16);
      }
#pragma unroll
      for (int m = 0; m < 2; ++m)
#pragma unroll
        for (int n = 0; n < 3; ++n)
          acc[m][n] = __builtin_amdgcn_mfma_f32_16x16x32_bf16(af[m], bfr[n],
                                                              acc[m][n], 0, 0, 0);
    }
  };

  STAGE(0, 0);
  __syncthreads();  // prologue drain
#pragma unroll
  for (int kt = 0; kt < 12; kt += 2) {
    if (kt + 1 < 12) STAGE(1, kt + 1);
    COMPUTE(0);
    __syncthreads();
    if (kt + 2 < 12) STAGE(0, kt + 2);
    COMPUTE(1);
    __syncthreads();
  }

  // ---- epilogue: write MFMA-native layouts ----
  if (z == 1) {
#pragma unroll
    for (int m = 0; m < 2; ++m) {
      const int tok0 = bm0 + wr * 32 + m * 16 + l4 * 4;
#pragma unroll
      for (int n = 0; n < 3; ++n) {
        const int d = bn0 + wc * 48 + n * 16 + l15;
        ushort4 pk;
        pk.x = f2bf(acc[m][n][0]); pk.y = f2bf(acc[m][n][1]);
        pk.z = f2bf(acc[m][n][2]); pk.w = f2bf(acc[m][n][3]);
        *(ushort4*)&vT_p[(((size_t)(tok0 >> 5) * EMB + d) << 5) + (tok0 & 31)] = pk;
      }
    }
  } else {
    unsigned short* __restrict__ dh = (z == 0) ? k_t : q_t;
#pragma unroll
    for (int m = 0; m < 2; ++m) {
      const int tok0 = bm0 + wr * 32 + m * 16 + l4 * 4;
#pragma unroll
      for (int n = 0; n < 3; ++n) {
        const int d = bn0 + wc * 48 + n * 16 + l15;
        const size_t base =
            (((size_t)(tok0 >> 4) * DCN + (d >> 5)) * 16) * 32 + (d & 31);
#pragma unroll
        for (int r = 0; r < 4; ++r)
          dh[base + (size_t)((tok0 & 15) + r) * 32] = f2bf(acc[m][n][r]);
      }
    }
  }
}

// ---------------- fused attention v2: 12 waves, wave-per-N-tile ------------
// 256 blocks = (qt 0..127) x (h 0..1); 768 threads = 12 waves (3/SIMD).
// Phase 1: wave w owns N-tile w (one MFMA chain; numerics == r14); P -> LDS
// + partial row sums. QK^T duplicated across the 2 h-blocks (cheap).
// Phase 2: wave w owns 32 d-cols of half h. No global P/Ssum traffic.
__global__ __launch_bounds__(768) void attn_fused(
    const unsigned short* __restrict__ k_t, const unsigned short* __restrict__ q_t,
    const unsigned short* __restrict__ vT_p, float* __restrict__ out) {
  const int bid = ((int)blockIdx.x & 7) * 32 + ((int)blockIdx.x >> 3);  // XCD
  const int qt = bid >> 1, h = bid & 1;
  const int tid = threadIdx.x, lane = tid & 63, w = tid / 64;  // 0..11
  const int l15 = lane & 15, l4 = lane >> 4;
  const int t0 = qt * 16;
  const int js0 = (t0 - 64) & ~31;  // 32-aligned slot base (maybe <0)

  __shared__ unsigned short P_l[6][16][32];  // 6KB
  __shared__ float ssum_l[12][16];
  __shared__ float rcp_l[16];

  const int foff = l15 * 32 + l4 * 8;
  const size_t a_base = (size_t)qt * DCN * 512 + foff;

  // ---- phase 1: wave w owns N-tile nt = w ----
  const int nt = w;
  const int tt = min(max((js0 >> 4) + nt, 0), TCN - 1);
  const size_t bb = (size_t)tt * DCN * 512 + foff;

  f32x4 s = {};
#pragma unroll
  for (int kk = 0; kk < DCN; ++kk) {
    const bf16x8 ah = *(const bf16x8*)&q_t[a_base + (size_t)kk * 512];
    const bf16x8 bv = *(const bf16x8*)&k_t[bb + (size_t)kk * 512];
    s = __builtin_amdgcn_mfma_f32_16x16x32_bf16(ah, bv, s, 0, 0, 0);
  }

  const float SC = 0.03608439182435161f;  // 768^-0.5
  const int qrow0 = t0 + l4 * 4;
  {
    const int j = js0 + nt * 16 + l15;
    float e[4];
#pragma unroll
    for (int r = 0; r < 4; ++r) {
      const int t = qrow0 + r;
      const bool ok = (j >= 0) && (j < TOK) && (j >= t - WIN) && (j <= t + WIN);
      e[r] = ok ? __expf(s[r] * SC) : 0.0f;
    }
#pragma unroll
    for (int r = 0; r < 4; ++r) {
      float sm = e[r];
#pragma unroll
      for (int off = 1; off < 16; off <<= 1) sm += __shfl_xor(sm, off);
      if (l15 == 0) ssum_l[nt][l4 * 4 + r] = sm;
    }
#pragma unroll
    for (int r = 0; r < 4; ++r)
      P_l[nt >> 1][l4 * 4 + r][(nt & 1) * 16 + l15] = f2bf(e[r]);
  }
  __syncthreads();

  if (tid < 16) {
    float s2 = 0.f;
#pragma unroll
    for (int i = 0; i < 12; ++i) s2 += ssum_l[i][tid];
    const int t = t0 + tid;
    const int len = min(TOK, t + WIN + 1) - max(0, t - WIN);
    rcp_l[tid] = 1.0f / (s2 * (float)len);
  }

  // ---- phase 2: PV, wave owns 32 d-cols: h*384 + w*32 .. +32 ----
  f32x4 o[2] = {};
  const int c0 = js0 >> 5;
#pragma unroll
  for (int kc = 0; kc < 6; ++kc) {
    const bf16x8 pa = *(const bf16x8*)&P_l[kc][l15][l4 * 8];
    const int cc = min(max(c0 + kc, 0), TOK / 32 - 1);  // clamp; P=0 masks
    const size_t vb = (size_t)cc * (EMB * 32);
#pragma unroll
    for (int n = 0; n < 2; ++n) {
      const int d = h * 384 + w * 32 + n * 16 + l15;
      const bf16x8 vbf = *(const bf16x8*)&vT_p[vb + (size_t)d * 32 + l4 * 8];
      o[n] = __builtin_amdgcn_mfma_f32_16x16x32_bf16(pa, vbf, o[n], 0, 0, 0);
    }
  }
  __syncthreads();  // rcp_l ready

  float rr[4];
#pragma unroll
  for (int r = 0; r < 4; ++r) rr[r] = rcp_l[l4 * 4 + r];
#pragma unroll
  for (int n = 0; n < 2; ++n) {
    const int d = h * 384 + w * 32 + n * 16 + l15;
#pragma unroll
    for (int r = 0; r < 4; ++r)
      out[(size_t)(qrow0 + r) * EMB + d] = o[n][r] * rr[r];
  }
}

extern "C" void kernel_launch(void* const* d_in, const int* in_sizes, int n_in,
                              void* d_out, int out_size, void* d_ws, size_t ws_size,
                              hipStream_t stream) {
  const float* key = (const float*)d_in[0];
  const float* value = (const float*)d_in[1];
  const float* query = (const float*)d_in[2];
  const float* Wk = (const float*)d_in[3];
  const float* Wv = (const float*)d_in[4];
  const float* Wq = (const float*)d_in[5];

  // ws layout (~22 MB): Ab | WT | k_t | q_t | vT_p
  unsigned short* ws = (unsigned short*)d_ws;
  const size_t NA = (size_t)3 * TOK * EMB;
  const size_t NW = (size_t)3 * EMB * EMB;
  const size_t NM = (size_t)TOK * EMB;
  unsigned short* Ab = ws;
  unsigned short* WT = Ab + NA;
  unsigned short* k_t = WT + NW;
  unsigned short* q_t = k_t + NM;
  unsigned short* vT_p = q_t + NM;
  float* out = (float*)d_out;

  prep<<<dim3(3 * TOK * EMB / 4 / 256, 1, 2), 256, 0, stream>>>(
      key, value, query, Wk, Wv, Wq, Ab, WT);
  proj_gemm<<<dim3(EMB / 96, TOK / 64, 3), 256, 0, stream>>>(
      Ab, WT, k_t, vT_p, q_t);
  attn_fused<<<256, 768, 0, stream>>>(k_t, q_t, vT_p, out);
}

// Round 17
// 41.210 us; speedup vs baseline: 1.2991x; 1.0853x over previous
//
#include <hip/hip_runtime.h>
#include <cstdint>

#define TOK 2048
#define EMB 768
#define WIN 64
#define TCN (TOK / 16) // 128 token tiles (16-row)
#define DCN (EMB / 32) // 24 d-chunks (32-col)

typedef __attribute__((ext_vector_type(8))) __bf16 bf16x8;
typedef __attribute__((ext_vector_type(4))) float f32x4;

static __device__ __forceinline__ unsigned short f2bf(float f) {
  uint32_t x = __float_as_uint(f);
  uint32_t r = (x + 0x7fffu + ((x >> 16) & 1u)) >> 16;  // RNE
  return (unsigned short)r;
}

static __device__ __forceinline__ void gload_lds16(const void* g, void* l) {
  __builtin_amdgcn_global_load_lds(
      (const __attribute__((address_space(1))) uint32_t*)g,
      (__attribute__((address_space(3))) uint32_t*)l, 16, 0, 0);
}

// ---------------- prep (1D grid, 3264 blocks) ----------------
// bx < 1536: inputs -> bf16 Ab; 3 independent cvt per thread (MLP).
// bx >= 1536: weights -> transposed bf16 WT[d][e] (vectorized, stride-33).
__global__ __launch_bounds__(256) void prep(
    const float* __restrict__ key, const float* __restrict__ value,
    const float* __restrict__ query, const float* __restrict__ Wk,
    const float* __restrict__ Wv, const float* __restrict__ Wq,
    unsigned short* __restrict__ Ab, unsigned short* __restrict__ WT) {
  __shared__ float t[32][33];
  const int bx = blockIdx.x, tid = threadIdx.x;
  if (bx < 1536) {
    const int64_t NE4 = (int64_t)TOK * EMB / 4;  // 393216 float4 per input
    const int64_t i = (int64_t)bx * 256 + tid;   // 0..393215
    const float4* __restrict__ s0 = (const float4*)key;
    const float4* __restrict__ s1 = (const float4*)value;
    const float4* __restrict__ s2 = (const float4*)query;
    const float4 x0 = s0[i], x1 = s1[i], x2 = s2[i];
    ushort4 h0, h1, h2;
    h0.x = f2bf(x0.x); h0.y = f2bf(x0.y); h0.z = f2bf(x0.z); h0.w = f2bf(x0.w);
    h1.x = f2bf(x1.x); h1.y = f2bf(x1.y); h1.z = f2bf(x1.z); h1.w = f2bf(x1.w);
    h2.x = f2bf(x2.x); h2.y = f2bf(x2.y); h2.z = f2bf(x2.z); h2.w = f2bf(x2.w);
    ((ushort4*)Ab)[i] = h0;
    ((ushort4*)Ab)[NE4 + i] = h1;
    ((ushort4*)Ab)[2 * NE4 + i] = h2;
  } else {
    const int rem0 = bx - 1536;  // 0..1727
    const int wz = rem0 / 576, rem = rem0 - wz * 576;
    const float* w = (wz == 0) ? Wk : (wz == 1) ? Wv : Wq;
    const int d0 = (rem % 24) * 32, e0 = (rem / 24) * 32;
    const int row = tid >> 3, c4 = (tid & 7) * 4;
    const float4 x = *(const float4*)&w[(size_t)(e0 + row) * EMB + d0 + c4];
    t[row][c4] = x.x; t[row][c4 + 1] = x.y;
    t[row][c4 + 2] = x.z; t[row][c4 + 3] = x.w;
    __syncthreads();
    // t[e][d] = W[e0+e][d0+d]; write WT[d][e] with ushort4 along e
    ushort4 pk;
    pk.x = f2bf(t[c4][row]); pk.y = f2bf(t[c4 + 1][row]);
    pk.z = f2bf(t[c4 + 2][row]); pk.w = f2bf(t[c4 + 3][row]);
    *(ushort4*)&WT[(size_t)wz * EMB * EMB + (size_t)(d0 + row) * EMB + e0 + c4] = pk;
  }
}

// ---------------- projections: bf16 MFMA GEMM, BK=64, dbuf, BN=96 ----------
// r12's proven kernel (best measured). STAGE(next) before COMPUTE(cur), one
// barrier per K-step; 768 blocks = 3.00/CU; T2 XOR involution on staging
// source + fragment read. Epilogue writes MFMA-native layouts:
//   z=0 (k), z=2 (q): bf16 tiled [tok/16][d/32][16][32]
//   z=1 (v): bf16 V^T panels [tok/32][768][32]
__global__ __launch_bounds__(256) void proj_gemm(
    const unsigned short* __restrict__ Ab, const unsigned short* __restrict__ WT,
    unsigned short* __restrict__ k_t, unsigned short* __restrict__ vT_p,
    unsigned short* __restrict__ q_t) {
  const int z = blockIdx.z;
  const int bn0 = blockIdx.x * 96;   // output col (D)
  const int bm0 = blockIdx.y * 64;   // output row (token)
  const int tid = threadIdx.x, lane = tid & 63, w = tid >> 6;
  const int wr = w >> 1, wc = w & 1;
  const int l15 = lane & 15, l4 = lane >> 4;

  __shared__ unsigned short lA[2][64 * 64];   // 2 x 8KB
  __shared__ unsigned short lB[2][96 * 64];   // 2 x 12KB

  const unsigned short* __restrict__ Ah = Ab + (size_t)z * TOK * EMB;
  const unsigned short* __restrict__ Bh = WT + (size_t)z * EMB * EMB;

  f32x4 acc[2][3] = {};

  const int srow = lane >> 3;                       // row within chunk group
  const int scol = ((lane & 7) ^ (srow & 7)) * 8;   // bf16 col (16B chunks)

  auto STAGE = [&](int b, int kt) {
    const int kk = kt * 64;
#pragma unroll
    for (int c = 0; c < 2; ++c) {
      const int ch = w * 2 + c;  // 8 A-chunks (64 rows)
      gload_lds16(Ah + (size_t)(bm0 + ch * 8 + srow) * EMB + kk + scol,
                  (char*)&lA[b][0] + ch * 1024);
    }
#pragma unroll
    for (int c = 0; c < 3; ++c) {
      const int ch = w * 3 + c;  // 12 B-chunks (96 rows)
      gload_lds16(Bh + (size_t)(bn0 + ch * 8 + srow) * EMB + kk + scol,
                  (char*)&lB[b][0] + ch * 1024);
    }
  };

  auto COMPUTE = [&](int b) {
#pragma unroll
    for (int ks = 0; ks < 2; ++ks) {
      bf16x8 af[2], bfr[3];
#pragma unroll
      for (int m = 0; m < 2; ++m) {
        const int R = wr * 32 + m * 16 + l15;
        const int sl = (ks * 4 + l4) ^ (R & 7);
        af[m] = *(const bf16x8*)((const char*)&lA[b][0] + R * 128 + sl * 16);
      }
#pragma unroll
      for (int n = 0; n < 3; ++n) {
        const int R = wc * 48 + n * 16 + l15;
        const int sl = (ks * 4 + l4) ^ (R & 7);
        bfr[n] = *(const bf16x8*)((const char*)&lB[b][0] + R * 128 + sl * 16);
      }
#pragma unroll
      for (int m = 0; m < 2; ++m)
#pragma unroll
        for (int n = 0; n < 3; ++n)
          acc[m][n] = __builtin_amdgcn_mfma_f32_16x16x32_bf16(af[m], bfr[n],
                                                              acc[m][n], 0, 0, 0);
    }
  };

  STAGE(0, 0);
  __syncthreads();  // prologue drain
#pragma unroll
  for (int kt = 0; kt < 12; kt += 2) {
    if (kt + 1 < 12) STAGE(1, kt + 1);
    COMPUTE(0);
    __syncthreads();
    if (kt + 2 < 12) STAGE(0, kt + 2);
    COMPUTE(1);
    __syncthreads();
  }

  // ---- epilogue: write MFMA-native layouts ----
  if (z == 1) {
#pragma unroll
    for (int m = 0; m < 2; ++m) {
      const int tok0 = bm0 + wr * 32 + m * 16 + l4 * 4;
#pragma unroll
      for (int n = 0; n < 3; ++n) {
        const int d = bn0 + wc * 48 + n * 16 + l15;
        ushort4 pk;
        pk.x = f2bf(acc[m][n][0]); pk.y = f2bf(acc[m][n][1]);
        pk.z = f2bf(acc[m][n][2]); pk.w = f2bf(acc[m][n][3]);
        *(ushort4*)&vT_p[(((size_t)(tok0 >> 5) * EMB + d) << 5) + (tok0 & 31)] = pk;
      }
    }
  } else {
    unsigned short* __restrict__ dh = (z == 0) ? k_t : q_t;
#pragma unroll
    for (int m = 0; m < 2; ++m) {
      const int tok0 = bm0 + wr * 32 + m * 16 + l4 * 4;
#pragma unroll
      for (int n = 0; n < 3; ++n) {
        const int d = bn0 + wc * 48 + n * 16 + l15;
        const size_t base =
            (((size_t)(tok0 >> 4) * DCN + (d >> 5)) * 16) * 32 + (d & 31);
#pragma unroll
        for (int r = 0; r < 4; ++r)
          dh[base + (size_t)((tok0 & 15) + r) * 32] = f2bf(acc[m][n][r]);
      }
    }
  }
}

// ---------------- fused attention (r14's best-measured 6-wave) -------------
// 256 blocks = (qt 0..127) x (h 0..1); 384 threads = 6 waves.
// Phase 1: wave w owns N-tiles {2w, 2w+1} (2 indep MFMA chains); P -> LDS
// + partial row sums. Phase 2: wave w owns 64 d-cols of half h.
__global__ __launch_bounds__(384) void attn_fused(
    const unsigned short* __restrict__ k_t, const unsigned short* __restrict__ q_t,
    const unsigned short* __restrict__ vT_p, float* __restrict__ out) {
  const int bid = ((int)blockIdx.x & 7) * 32 + ((int)blockIdx.x >> 3);  // XCD
  const int qt = bid >> 1, h = bid & 1;
  const int tid = threadIdx.x, lane = tid & 63, w = tid / 64;  // 0..5
  const int l15 = lane & 15, l4 = lane >> 4;
  const int t0 = qt * 16;
  const int js0 = (t0 - 64) & ~31;  // 32-aligned slot base (maybe <0)

  __shared__ unsigned short P_l[6][16][32];  // 6KB
  __shared__ float ssum_l[12][16];
  __shared__ float rcp_l[16];

  const int foff = l15 * 32 + l4 * 8;
  const size_t a_base = (size_t)qt * DCN * 512 + foff;

  // ---- phase 1: QK^T for N-tiles 2w, 2w+1 ----
  const int tt0 = min(max((js0 >> 4) + 2 * w, 0), TCN - 1);
  const int tt1 = min(max((js0 >> 4) + 2 * w + 1, 0), TCN - 1);
  const size_t b0 = (size_t)tt0 * DCN * 512 + foff;
  const size_t b1 = (size_t)tt1 * DCN * 512 + foff;

  f32x4 s0 = {}, s1 = {};
#pragma unroll
  for (int kk = 0; kk < DCN; ++kk) {
    const bf16x8 ah = *(const bf16x8*)&q_t[a_base + (size_t)kk * 512];
    const bf16x8 bb0 = *(const bf16x8*)&k_t[b0 + (size_t)kk * 512];
    const bf16x8 bb1 = *(const bf16x8*)&k_t[b1 + (size_t)kk * 512];
    s0 = __builtin_amdgcn_mfma_f32_16x16x32_bf16(ah, bb0, s0, 0, 0, 0);
    s1 = __builtin_amdgcn_mfma_f32_16x16x32_bf16(ah, bb1, s1, 0, 0, 0);
  }

  const float SC = 0.03608439182435161f;  // 768^-0.5
  const int qrow0 = t0 + l4 * 4;
#pragma unroll
  for (int half = 0; half < 2; ++half) {
    const int nt = 2 * w + half;
    const f32x4 sv = half ? s1 : s0;
    const int j = js0 + nt * 16 + l15;
    float e[4];
#pragma unroll
    for (int r = 0; r < 4; ++r) {
      const int t = qrow0 + r;
      const bool ok = (j >= 0) && (j < TOK) && (j >= t - WIN) && (j <= t + WIN);
      e[r] = ok ? __expf(sv[r] * SC) : 0.0f;
    }
#pragma unroll
    for (int r = 0; r < 4; ++r) {
      float sm = e[r];
#pragma unroll
      for (int off = 1; off < 16; off <<= 1) sm += __shfl_xor(sm, off);
      if (l15 == 0) ssum_l[nt][l4 * 4 + r] = sm;
    }
#pragma unroll
    for (int r = 0; r < 4; ++r)
      P_l[w][l4 * 4 + r][half * 16 + l15] = f2bf(e[r]);
  }
  __syncthreads();

  if (tid < 16) {
    float s = 0.f;
#pragma unroll
    for (int i = 0; i < 12; ++i) s += ssum_l[i][tid];
    const int t = t0 + tid;
    const int len = min(TOK, t + WIN + 1) - max(0, t - WIN);
    rcp_l[tid] = 1.0f / (s * (float)len);
  }

  // ---- phase 2: PV, wave owns d-cols h*384 + w*64 .. +64 ----
  f32x4 o[4] = {};
  const int c0 = js0 >> 5;
#pragma unroll
  for (int kc = 0; kc < 6; ++kc) {
    const bf16x8 pa = *(const bf16x8*)&P_l[kc][l15][l4 * 8];
    const int cc = min(max(c0 + kc, 0), TOK / 32 - 1);  // clamp; P=0 masks
    const size_t vb = (size_t)cc * (EMB * 32);
#pragma unroll
    for (int n = 0; n < 4; ++n) {
      const int d = h * 384 + w * 64 + n * 16 + l15;
      const bf16x8 vbf = *(const bf16x8*)&vT_p[vb + (size_t)d * 32 + l4 * 8];
      o[n] = __builtin_amdgcn_mfma_f32_16x16x32_bf16(pa, vbf, o[n], 0, 0, 0);
    }
  }
  __syncthreads();  // rcp_l ready

  float rr[4];
#pragma unroll
  for (int r = 0; r < 4; ++r) rr[r] = rcp_l[l4 * 4 + r];
#pragma unroll
  for (int n = 0; n < 4; ++n) {
    const int d = h * 384 + w * 64 + n * 16 + l15;
#pragma unroll
    for (int r = 0; r < 4; ++r)
      out[(size_t)(qrow0 + r) * EMB + d] = o[n][r] * rr[r];
  }
}

extern "C" void kernel_launch(void* const* d_in, const int* in_sizes, int n_in,
                              void* d_out, int out_size, void* d_ws, size_t ws_size,
                              hipStream_t stream) {
  const float* key = (const float*)d_in[0];
  const float* value = (const float*)d_in[1];
  const float* query = (const float*)d_in[2];
  const float* Wk = (const float*)d_in[3];
  const float* Wv = (const float*)d_in[4];
  const float* Wq = (const float*)d_in[5];

  // ws layout (~22 MB): Ab | WT | k_t | q_t | vT_p
  unsigned short* ws = (unsigned short*)d_ws;
  const size_t NA = (size_t)3 * TOK * EMB;
  const size_t NW = (size_t)3 * EMB * EMB;
  const size_t NM = (size_t)TOK * EMB;
  unsigned short* Ab = ws;
  unsigned short* WT = Ab + NA;
  unsigned short* k_t = WT + NW;
  unsigned short* q_t = k_t + NM;
  unsigned short* vT_p = q_t + NM;
  float* out = (float*)d_out;

  prep<<<3264, 256, 0, stream>>>(key, value, query, Wk, Wv, Wq, Ab, WT);
  proj_gemm<<<dim3(EMB / 96, TOK / 64, 3), 256, 0, stream>>>(
      Ab, WT, k_t, vT_p, q_t);
  attn_fused<<<256, 384, 0, stream>>>(k_t, q_t, vT_p, out);
}